// Round 6
// baseline (1582.001 us; speedup 1.0000x reference)
//
#include <hip/hip_runtime.h>
#include <math.h>

#define GAMMA 0.1f

typedef float f32x4 __attribute__((ext_vector_type(4)));
typedef short short8 __attribute__((ext_vector_type(8)));

static __device__ __forceinline__ unsigned short f2bf(float f) {
  union { float f; unsigned u; } v; v.f = f;
  unsigned r = v.u + 0x7FFF + ((v.u >> 16) & 1);   // RNE
  return (unsigned short)(r >> 16);
}
static __device__ __forceinline__ float bf2f(unsigned short b) {
  union { unsigned u; float f; } v; v.u = ((unsigned)b) << 16;
  return v.f;
}

// ---------------------------------------------------------------------------
// Build transposed bf16 B matrix: Bt[c][k], c in [0,COLS), k in [0,KPAD)
//   c < H : W[k][c];  c == H : sc[k];  c == H+1 : dk[k];  else/k>=Kact : 0
// ---------------------------------------------------------------------------
__global__ __launch_bounds__(256) void build_bt(
    const float* __restrict__ W, const float* __restrict__ sc,
    const float* __restrict__ dk, unsigned short* __restrict__ Bt,
    int H, int Kact, int KPAD, int COLS) {
  int i = blockIdx.x * 256 + threadIdx.x;
  if (i >= COLS * KPAD) return;
  int c = i / KPAD;
  int k = i - c * KPAD;
  float v = 0.f;
  if (k < Kact) {
    if (c < H) v = W[(size_t)k * H + c];
    else if (c == H) v = sc[k];
    else if (c == H + 1) v = dk[k];
  }
  Bt[i] = f2bf(v);
}

// ---------------------------------------------------------------------------
// Fused MFMA linear: out = A @ W (bf16 out), s = sigmoid(A@sc+sb), Dk = A@dk+db
// Block = 256 threads (4 waves), each wave owns 16 rows, all CFRAGS*16 cols.
// mfma_f32_16x16x32_bf16 lane mapping (m89-verified):
//   A: lane l -> A[l&15][kb + (l>>4)*8 + j];  B via Bt[l&15][...]
//   D: lane l, reg r -> D[(l>>4)*4 + r][l&15]
// ---------------------------------------------------------------------------
template <int KPAD, int CFRAGS, int OUTFRAGS, bool ABF>
__global__ __launch_bounds__(256) void mfma_linear(
    const void* __restrict__ Aptr, const unsigned short* __restrict__ Bt,
    const float* __restrict__ sb, const float* __restrict__ db,
    unsigned short* __restrict__ outW, float* __restrict__ s,
    float* __restrict__ Dk, int N, int Kact) {
  constexpr int H = OUTFRAGS * 16;
  const int w = threadIdx.x >> 6;
  const int l = threadIdx.x & 63;
  const int kgrp = l >> 4;          // 0..3
  const int lc = l & 15;
  const int rowA = blockIdx.x * 64 + w * 16 + lc;       // A-fragment row
  const int rowD = blockIdx.x * 64 + w * 16 + kgrp * 4; // D rows base

  f32x4 acc[CFRAGS];
#pragma unroll
  for (int i = 0; i < CFRAGS; ++i) acc[i] = (f32x4)0.f;

  for (int ks = 0; ks < KPAD / 32; ++ks) {
    const int kb = ks * 32 + kgrp * 8;
    short8 av;
    if (rowA < N) {
      if (ABF) {
        av = *(const short8*)((const unsigned short*)Aptr +
                              (size_t)rowA * Kact + kb);
      } else {
        const float* A = (const float*)Aptr + (size_t)rowA * Kact;
        if (kb + 8 <= Kact) {
          f32x4 f0 = *(const f32x4*)(A + kb);
          f32x4 f1 = *(const f32x4*)(A + kb + 4);
#pragma unroll
          for (int j = 0; j < 4; ++j) {
            av[j] = (short)f2bf(f0[j]);
            av[j + 4] = (short)f2bf(f1[j]);
          }
        } else {
#pragma unroll
          for (int j = 0; j < 8; ++j) {
            int f = kb + j;
            av[j] = (short)f2bf(f < Kact ? A[f] : 0.f);
          }
        }
      }
    } else {
#pragma unroll
      for (int j = 0; j < 8; ++j) av[j] = 0;
    }

#pragma unroll
    for (int fc = 0; fc < CFRAGS; ++fc) {
      short8 bv = *(const short8*)(Bt + (size_t)(fc * 16 + lc) * KPAD + kb);
      acc[fc] = __builtin_amdgcn_mfma_f32_16x16x32_bf16(av, bv, acc[fc], 0, 0, 0);
    }
  }

  // epilogue: xW (bf16)
#pragma unroll
  for (int fc = 0; fc < OUTFRAGS; ++fc) {
#pragma unroll
    for (int r = 0; r < 4; ++r) {
      int gr = rowD + r;
      if (gr < N) outW[(size_t)gr * H + fc * 16 + lc] = f2bf(acc[fc][r]);
    }
  }
  // gate + degree columns live in the last fragment (local cols 0 and 1)
  if (lc < 2) {
    f32x4 g = acc[CFRAGS - 1];
#pragma unroll
    for (int r = 0; r < 4; ++r) {
      int gr = rowD + r;
      if (gr < N) {
        if (lc == 0) s[gr] = 1.f / (1.f + expf(-(g[r] + sb[0])));
        else Dk[gr] = g[r] + db[0];
      }
    }
  }
}

// ---------------------------------------------------------------------------
// Tile binning: bucket = dst >> 7 (128-node tiles). nb <= 512 assumed.
// ---------------------------------------------------------------------------
#define BIN_CHUNK 4096

__global__ __launch_bounds__(256) void bucket_count(
    const int* __restrict__ ei, int E, int* __restrict__ bcnt) {
  __shared__ int lc[512];
  for (int i = threadIdx.x; i < 512; i += 256) lc[i] = 0;
  __syncthreads();
  const int base = blockIdx.x * BIN_CHUNK;
  for (int k = threadIdx.x; k < BIN_CHUNK; k += 256) {
    int e = base + k;
    if (e < E) atomicAdd(&lc[ei[E + e] >> 7], 1);
  }
  __syncthreads();
  for (int b = threadIdx.x; b < 512; b += 256)
    if (lc[b]) atomicAdd(&bcnt[b], lc[b]);
}

// single block: exclusive scan of nb bucket counts -> boff[0..nb], gcur init
__global__ __launch_bounds__(512) void bucket_scan(
    const int* __restrict__ bcnt, int nb, int* __restrict__ boff,
    int* __restrict__ gcur) {
  __shared__ int sh[512];
  int t = threadIdx.x;
  int v = (t < nb) ? bcnt[t] : 0;
  sh[t] = v;
  __syncthreads();
  int acc = v;
  for (int off = 1; off < 512; off <<= 1) {
    int xx = (t >= off) ? sh[t - off] : 0;
    __syncthreads();
    acc += xx;
    sh[t] = acc;
    __syncthreads();
  }
  if (t < nb) {
    boff[t] = acc - v;
    gcur[t] = acc - v;
  }
  if (t == nb - 1) boff[nb] = acc;
}

// bin-fill: stage chunk in LDS, count per bucket, reserve contiguous runs via
// one global atomic per (wg,bucket), then write records run-contiguously.
// Record: {x = (dst_local<<16) | src  (src < 65536!), y = fp32 weight bits}
__global__ __launch_bounds__(256) void bin_fill(
    const int* __restrict__ ei, const float* __restrict__ ew, int E,
    int* __restrict__ gcur, int2* __restrict__ rec) {
  __shared__ int2 se[BIN_CHUNK];
  __shared__ int scnt[512];
  __shared__ int scur[512];
  for (int i = threadIdx.x; i < 512; i += 256) scnt[i] = 0;
  __syncthreads();
  const int base = blockIdx.x * BIN_CHUNK;
  for (int k = threadIdx.x; k < BIN_CHUNK; k += 256) {
    int e = base + k;
    if (e < E) {
      int src = ei[e];
      int dst = ei[E + e];
      se[k] = make_int2(src, dst);
      atomicAdd(&scnt[dst >> 7], 1);
    }
  }
  __syncthreads();
  for (int b = threadIdx.x; b < 512; b += 256)
    if (scnt[b]) scur[b] = atomicAdd(&gcur[b], scnt[b]);
  __syncthreads();
  for (int k = threadIdx.x; k < BIN_CHUNK; k += 256) {
    int e = base + k;
    if (e < E) {
      int2 sd = se[k];
      int b = sd.y >> 7;
      int pos = atomicAdd(&scur[b], 1);
      rec[pos] = make_int2(((sd.y & 127) << 16) | sd.x, __float_as_int(ew[e]));
    }
  }
}

// ---------------------------------------------------------------------------
// Fused tile aggregation + combine. One block per 128-node dst tile.
// lA/lK accumulated via LDS atomics; epilogue applies gate/Dk combine.
// ---------------------------------------------------------------------------
template <int H>
static __device__ __forceinline__ void agg_rows(
    const int2* __restrict__ rec, int lo, int hi, int slot, int h,
    const unsigned short* __restrict__ feat, float* __restrict__ l) {
  constexpr int SLOTS = 16 * (64 / H);   // concurrent edge slots per block
  for (int j = lo + slot; j < hi; j += SLOTS * 8) {
    int2 r[8];
#pragma unroll
    for (int u = 0; u < 8; ++u) {
      int jj = j + u * SLOTS;
      r[u] = (jj < hi) ? rec[jj] : make_int2(0, 0);  // w=0 dummy: adds 0.0f
    }
    float f[8];
#pragma unroll
    for (int u = 0; u < 8; ++u)
      f[u] = bf2f(feat[(size_t)(r[u].x & 0xFFFF) * H + h]);
#pragma unroll
    for (int u = 0; u < 8; ++u)
      atomicAdd(&l[(r[u].x >> 16) * H + h], __int_as_float(r[u].y) * f[u]);
  }
}

template <int H, bool OUTF32>
__global__ __launch_bounds__(1024) void agg_fused(
    const int2* __restrict__ recA, const int* __restrict__ boffA,
    const int2* __restrict__ recK, const int* __restrict__ boffK,
    const unsigned short* __restrict__ feat, const float* __restrict__ s,
    const float* __restrict__ Dk, void* __restrict__ outp, int N) {
  constexpr int TN = 128;
  __shared__ float lA[TN * H];
  __shared__ float lK[TN * H];
  const int tile = blockIdx.x;
  const int node0 = tile * TN;
  for (int i = threadIdx.x; i < TN * H; i += 1024) {
    lA[i] = 0.f;
    lK[i] = 0.f;
  }
  __syncthreads();

  const int wid = threadIdx.x >> 6;
  const int lane = threadIdx.x & 63;
  const int sub = lane / H;            // 0 for H=64; 0..3 for H=16
  const int h = lane % H;
  const int slot = wid * (64 / H) + sub;

  agg_rows<H>(recA, boffA[tile], boffA[tile + 1], slot, h, feat, lA);
  agg_rows<H>(recK, boffK[tile], boffK[tile + 1], slot, h, feat, lK);
  __syncthreads();

  for (int idx = threadIdx.x; idx < TN * H; idx += 1024) {
    int rrow = idx / H;
    int h2 = idx % H;
    int n = node0 + rrow;
    if (n < N) {
      float sv = s[n];
      float val = sv * lA[idx] + (1.f - sv) * lK[idx] +
                  GAMMA * Dk[n] * bf2f(feat[(size_t)n * H + h2]);
      if (OUTF32) ((float*)outp)[(size_t)n * H + h2] = val;
      else ((unsigned short*)outp)[(size_t)n * H + h2] = f2bf(val);
    }
  }
}

// ---------------------------------------------------------------------------
extern "C" void kernel_launch(void* const* d_in, const int* in_sizes, int n_in,
                              void* d_out, int out_size, void* d_ws, size_t ws_size,
                              hipStream_t stream) {
  const float* x = (const float*)d_in[0];
  const int* edge_index = (const int*)d_in[1];
  const float* edge_weight = (const float*)d_in[2];
  const int* knn_edge_index = (const int*)d_in[3];
  const float* knn_edge_weight = (const float*)d_in[4];
  const float* W0 = (const float*)d_in[5];
  const float* W1 = (const float*)d_in[6];
  const float* score0 = (const float*)d_in[7];
  const float* sbias0 = (const float*)d_in[8];
  const float* score1 = (const float*)d_in[9];
  const float* sbias1 = (const float*)d_in[10];
  const float* Dk0 = (const float*)d_in[11];
  const float* Dbias0 = (const float*)d_in[12];
  const float* Dk1 = (const float*)d_in[13];
  const float* Dbias1 = (const float*)d_in[14];

  const int F = in_sizes[7];          // 500
  const int N = in_sizes[0] / F;      // 50000  (must be < 65536: src packed in 16 bits)
  const int E = in_sizes[2];          // 1.6M
  const int Ek = in_sizes[4];         // 1.0M
  (void)n_in; (void)ws_size; (void)out_size;

  const int nb = (N + 127) / 128;     // 391 dst tiles (<= 512)

  // ---- workspace bump allocator (256B-aligned slices) ----
  char* cur = (char*)d_ws;
  auto alloc = [&](size_t bytes) {
    char* p = cur;
    cur += (bytes + 255) & ~(size_t)255;
    return (void*)p;
  };
  float* sbuf = (float*)alloc((size_t)N * 4);
  float* dkbuf = (float*)alloc((size_t)N * 4);
  // counts as ONE contiguous slice so a single memset zeroes both exactly
  int* bcnt2 = (int*)alloc((size_t)2 * nb * 4);
  int* bcntA = bcnt2;
  int* bcntK = bcnt2 + nb;
  int* boffA = (int*)alloc((size_t)(nb + 1) * 4);
  int* boffK = (int*)alloc((size_t)(nb + 1) * 4);
  int* gcurA = (int*)alloc((size_t)nb * 4);
  int* gcurK = (int*)alloc((size_t)nb * 4);
  int2* recA = (int2*)alloc((size_t)E * 8);
  int2* recK = (int2*)alloc((size_t)Ek * 8);
  unsigned short* Bt0 = (unsigned short*)alloc((size_t)80 * 512 * 2);
  unsigned short* Bt1 = (unsigned short*)alloc((size_t)32 * 64 * 2);
  unsigned short* xWb = (unsigned short*)alloc((size_t)N * 64 * 2);
  unsigned short* x1b = (unsigned short*)alloc((size_t)N * 64 * 2);
  unsigned short* xW1b = (unsigned short*)alloc((size_t)N * 16 * 2);

  // ---- B transposes (tiny) ----
  build_bt<<<(80 * 512 + 255) / 256, 256, 0, stream>>>(W0, score0, Dk0, Bt0,
                                                       64, F, 512, 80);
  build_bt<<<(32 * 64 + 255) / 256, 256, 0, stream>>>(W1, score1, Dk1, Bt1,
                                                      16, 64, 64, 32);

  // ---- tile binning (reused by both layers) ----
  hipMemsetAsync(bcnt2, 0, (size_t)2 * nb * sizeof(int), stream);
  const int nchA = (E + BIN_CHUNK - 1) / BIN_CHUNK;
  const int nchK = (Ek + BIN_CHUNK - 1) / BIN_CHUNK;
  bucket_count<<<nchA, 256, 0, stream>>>(edge_index, E, bcntA);
  bucket_count<<<nchK, 256, 0, stream>>>(knn_edge_index, Ek, bcntK);
  bucket_scan<<<1, 512, 0, stream>>>(bcntA, nb, boffA, gcurA);
  bucket_scan<<<1, 512, 0, stream>>>(bcntK, nb, boffK, gcurK);
  bin_fill<<<nchA, 256, 0, stream>>>(edge_index, edge_weight, E, gcurA, recA);
  bin_fill<<<nchK, 256, 0, stream>>>(knn_edge_index, knn_edge_weight, Ek,
                                     gcurK, recK);

  const int gemmBlocks = (N + 63) / 64;

  // ---- Layer 0: F=500 -> H=64 (+gate+Dk) ----
  mfma_linear<512, 5, 4, false><<<gemmBlocks, 256, 0, stream>>>(
      x, Bt0, sbias0, Dbias0, xWb, sbuf, dkbuf, N, F);
  agg_fused<64, false><<<nb, 1024, 0, stream>>>(recA, boffA, recK, boffK, xWb,
                                                sbuf, dkbuf, x1b, N);

  // ---- Layer 1: H=64 -> O=16 (+gate+Dk) ----
  mfma_linear<64, 2, 1, true><<<gemmBlocks, 256, 0, stream>>>(
      x1b, Bt1, sbias1, Dbias1, xW1b, sbuf, dkbuf, N, 64);
  agg_fused<16, true><<<nb, 1024, 0, stream>>>(recA, boffA, recK, boffK, xW1b,
                                               sbuf, dkbuf, d_out, N);
}

// Round 7
// 277.898 us; speedup vs baseline: 5.6927x; 5.6927x over previous
//
#include <hip/hip_runtime.h>
#include <math.h>

#define GAMMA 0.1f

typedef float f32x4 __attribute__((ext_vector_type(4)));
typedef short short8 __attribute__((ext_vector_type(8)));

static __device__ __forceinline__ unsigned short f2bf(float f) {
  union { float f; unsigned u; } v; v.f = f;
  unsigned r = v.u + 0x7FFF + ((v.u >> 16) & 1);   // RNE
  return (unsigned short)(r >> 16);
}
static __device__ __forceinline__ float bf2f(unsigned short b) {
  union { unsigned u; float f; } v; v.u = ((unsigned)b) << 16;
  return v.f;
}

// ---------------------------------------------------------------------------
// Build transposed bf16 B matrix: Bt[c][k], c in [0,COLS), k in [0,KPAD)
//   c < H : W[k][c];  c == H : sc[k];  c == H+1 : dk[k];  else/k>=Kact : 0
// ---------------------------------------------------------------------------
__global__ __launch_bounds__(256) void build_bt(
    const float* __restrict__ W, const float* __restrict__ sc,
    const float* __restrict__ dk, unsigned short* __restrict__ Bt,
    int H, int Kact, int KPAD, int COLS) {
  int i = blockIdx.x * 256 + threadIdx.x;
  if (i >= COLS * KPAD) return;
  int c = i / KPAD;
  int k = i - c * KPAD;
  float v = 0.f;
  if (k < Kact) {
    if (c < H) v = W[(size_t)k * H + c];
    else if (c == H) v = sc[k];
    else if (c == H + 1) v = dk[k];
  }
  Bt[i] = f2bf(v);
}

// ---------------------------------------------------------------------------
// Fused MFMA linear: out = A @ W (bf16 out), s = sigmoid(A@sc+sb), Dk = A@dk+db
// Block = 256 threads (4 waves), each wave owns 16 rows, all CFRAGS*16 cols.
// mfma_f32_16x16x32_bf16 lane mapping (m89-verified).
// ---------------------------------------------------------------------------
template <int KPAD, int CFRAGS, int OUTFRAGS, bool ABF>
__global__ __launch_bounds__(256) void mfma_linear(
    const void* __restrict__ Aptr, const unsigned short* __restrict__ Bt,
    const float* __restrict__ sb, const float* __restrict__ db,
    unsigned short* __restrict__ outW, float* __restrict__ s,
    float* __restrict__ Dk, int N, int Kact) {
  constexpr int H = OUTFRAGS * 16;
  const int w = threadIdx.x >> 6;
  const int l = threadIdx.x & 63;
  const int kgrp = l >> 4;          // 0..3
  const int lc = l & 15;
  const int rowA = blockIdx.x * 64 + w * 16 + lc;       // A-fragment row
  const int rowD = blockIdx.x * 64 + w * 16 + kgrp * 4; // D rows base

  f32x4 acc[CFRAGS];
#pragma unroll
  for (int i = 0; i < CFRAGS; ++i) acc[i] = (f32x4)0.f;

  for (int ks = 0; ks < KPAD / 32; ++ks) {
    const int kb = ks * 32 + kgrp * 8;
    short8 av;
    if (rowA < N) {
      if (ABF) {
        av = *(const short8*)((const unsigned short*)Aptr +
                              (size_t)rowA * Kact + kb);
      } else {
        const float* A = (const float*)Aptr + (size_t)rowA * Kact;
        if (kb + 8 <= Kact) {
          f32x4 f0 = *(const f32x4*)(A + kb);
          f32x4 f1 = *(const f32x4*)(A + kb + 4);
#pragma unroll
          for (int j = 0; j < 4; ++j) {
            av[j] = (short)f2bf(f0[j]);
            av[j + 4] = (short)f2bf(f1[j]);
          }
        } else {
#pragma unroll
          for (int j = 0; j < 8; ++j) {
            int f = kb + j;
            av[j] = (short)f2bf(f < Kact ? A[f] : 0.f);
          }
        }
      }
    } else {
#pragma unroll
      for (int j = 0; j < 8; ++j) av[j] = 0;
    }

#pragma unroll
    for (int fc = 0; fc < CFRAGS; ++fc) {
      short8 bv = *(const short8*)(Bt + (size_t)(fc * 16 + lc) * KPAD + kb);
      acc[fc] = __builtin_amdgcn_mfma_f32_16x16x32_bf16(av, bv, acc[fc], 0, 0, 0);
    }
  }

  // epilogue: xW (bf16)
#pragma unroll
  for (int fc = 0; fc < OUTFRAGS; ++fc) {
#pragma unroll
    for (int r = 0; r < 4; ++r) {
      int gr = rowD + r;
      if (gr < N) outW[(size_t)gr * H + fc * 16 + lc] = f2bf(acc[fc][r]);
    }
  }
  // gate + degree columns live in the last fragment (local cols 0 and 1)
  if (lc < 2) {
    f32x4 g = acc[CFRAGS - 1];
#pragma unroll
    for (int r = 0; r < 4; ++r) {
      int gr = rowD + r;
      if (gr < N) {
        if (lc == 0) s[gr] = 1.f / (1.f + expf(-(g[r] + sb[0])));
        else Dk[gr] = g[r] + db[0];
      }
    }
  }
}

// ---------------------------------------------------------------------------
// Tile binning: bucket = dst >> 7 (128-node tiles). nb <= 512 assumed.
// All histogram/cursor atomics are INT (native ds_add/global add) — never
// fp32 (R5 lesson: LDS fp32 atomicAdd -> CAS loop -> 26x slowdown).
// ---------------------------------------------------------------------------
#define BIN_CHUNK 4096

__global__ __launch_bounds__(256) void bucket_count(
    const int* __restrict__ ei, int E, int* __restrict__ bcnt) {
  __shared__ int lc[512];
  for (int i = threadIdx.x; i < 512; i += 256) lc[i] = 0;
  __syncthreads();
  const int base = blockIdx.x * BIN_CHUNK;
  for (int k = threadIdx.x; k < BIN_CHUNK; k += 256) {
    int e = base + k;
    if (e < E) atomicAdd(&lc[ei[E + e] >> 7], 1);
  }
  __syncthreads();
  for (int b = threadIdx.x; b < 512; b += 256)
    if (lc[b]) atomicAdd(&bcnt[b], lc[b]);
}

// single block: exclusive scan of nb bucket counts -> boff[0..nb], gcur init
__global__ __launch_bounds__(512) void bucket_scan(
    const int* __restrict__ bcnt, int nb, int* __restrict__ boff,
    int* __restrict__ gcur) {
  __shared__ int sh[512];
  int t = threadIdx.x;
  int v = (t < nb) ? bcnt[t] : 0;
  sh[t] = v;
  __syncthreads();
  int acc = v;
  for (int off = 1; off < 512; off <<= 1) {
    int xx = (t >= off) ? sh[t - off] : 0;
    __syncthreads();
    acc += xx;
    sh[t] = acc;
    __syncthreads();
  }
  if (t < nb) {
    boff[t] = acc - v;
    gcur[t] = acc - v;
  }
  if (t == nb - 1) boff[nb] = acc;
}

// bin-fill: stage chunk in LDS, count per bucket, reserve contiguous runs via
// one global atomic per (wg,bucket), then write records run-contiguously.
// Record: {x = (dst_local<<16) | src  (src < 65536!), y = fp32 weight bits}
__global__ __launch_bounds__(256) void bin_fill(
    const int* __restrict__ ei, const float* __restrict__ ew, int E,
    int* __restrict__ gcur, int2* __restrict__ rec) {
  __shared__ int2 se[BIN_CHUNK];
  __shared__ int scnt[512];
  __shared__ int scur[512];
  for (int i = threadIdx.x; i < 512; i += 256) scnt[i] = 0;
  __syncthreads();
  const int base = blockIdx.x * BIN_CHUNK;
  for (int k = threadIdx.x; k < BIN_CHUNK; k += 256) {
    int e = base + k;
    if (e < E) {
      int src = ei[e];
      int dst = ei[E + e];
      se[k] = make_int2(src, dst);
      atomicAdd(&scnt[dst >> 7], 1);
    }
  }
  __syncthreads();
  for (int b = threadIdx.x; b < 512; b += 256)
    if (scnt[b]) scur[b] = atomicAdd(&gcur[b], scnt[b]);
  __syncthreads();
  for (int k = threadIdx.x; k < BIN_CHUNK; k += 256) {
    int e = base + k;
    if (e < E) {
      int2 sd = se[k];
      int b = sd.y >> 7;
      int pos = atomicAdd(&scur[b], 1);
      rec[pos] = make_int2(((sd.y & 127) << 16) | sd.x, __float_as_int(ew[e]));
    }
  }
}

// ---------------------------------------------------------------------------
// tile_sort: one block per tile. Exact per-dst CSR within the tile's
// contiguous record span (single-XCD writes -> no write amplification).
// Emits row_ptr. INT LDS atomics only.
// ---------------------------------------------------------------------------
__global__ __launch_bounds__(256) void tile_sort(
    const int2* __restrict__ recRaw, const int* __restrict__ boff,
    int2* __restrict__ recS, int* __restrict__ rp, int N, int nb) {
  __shared__ int cnt[128];
  __shared__ int sc[128];
  __shared__ int cur[128];
  const int tile = blockIdx.x;
  const int lo = boff[tile], hi = boff[tile + 1];
  const int t = threadIdx.x;
  if (t < 128) cnt[t] = 0;
  __syncthreads();
  for (int j = lo + t; j < hi; j += 256)
    atomicAdd(&cnt[recRaw[j].x >> 16], 1);
  __syncthreads();
  if (t < 128) sc[t] = cnt[t];
  __syncthreads();
  for (int off = 1; off < 128; off <<= 1) {
    int v = 0;
    if (t < 128 && t >= off) v = sc[t - off];
    __syncthreads();
    if (t < 128) sc[t] += v;
    __syncthreads();
  }
  if (t < 128) {
    int excl = sc[t] - cnt[t];
    cur[t] = excl;
    int n = tile * 128 + t;
    if (n < N) rp[n] = lo + excl;
  }
  if (tile == nb - 1 && t == 0) rp[N] = hi;
  __syncthreads();
  for (int j = lo + t; j < hi; j += 256) {
    int2 r = recRaw[j];
    int pos = lo + atomicAdd(&cur[r.x >> 16], 1);
    recS[pos] = r;
  }
}

// ---------------------------------------------------------------------------
// Gather-sum over one CSR row with 8 independent chains (MLP).
// Record src is in the low 16 bits of .x.
// ---------------------------------------------------------------------------
template <int H>
static __device__ __forceinline__ float gather_sum(
    const int* __restrict__ rp, const int2* __restrict__ rec,
    const unsigned short* __restrict__ feat, int n, int h) {
  int b = rp[n], e = rp[n + 1];
  float a0 = 0.f, a1 = 0.f, a2 = 0.f, a3 = 0.f;
  float a4 = 0.f, a5 = 0.f, a6 = 0.f, a7 = 0.f;
  int j = b;
  for (; j + 8 <= e; j += 8) {
    int2 r0 = rec[j + 0];
    int2 r1 = rec[j + 1];
    int2 r2 = rec[j + 2];
    int2 r3 = rec[j + 3];
    int2 r4 = rec[j + 4];
    int2 r5 = rec[j + 5];
    int2 r6 = rec[j + 6];
    int2 r7 = rec[j + 7];
    a0 += __int_as_float(r0.y) * bf2f(feat[(size_t)(r0.x & 0xFFFF) * H + h]);
    a1 += __int_as_float(r1.y) * bf2f(feat[(size_t)(r1.x & 0xFFFF) * H + h]);
    a2 += __int_as_float(r2.y) * bf2f(feat[(size_t)(r2.x & 0xFFFF) * H + h]);
    a3 += __int_as_float(r3.y) * bf2f(feat[(size_t)(r3.x & 0xFFFF) * H + h]);
    a4 += __int_as_float(r4.y) * bf2f(feat[(size_t)(r4.x & 0xFFFF) * H + h]);
    a5 += __int_as_float(r5.y) * bf2f(feat[(size_t)(r5.x & 0xFFFF) * H + h]);
    a6 += __int_as_float(r6.y) * bf2f(feat[(size_t)(r6.x & 0xFFFF) * H + h]);
    a7 += __int_as_float(r7.y) * bf2f(feat[(size_t)(r7.x & 0xFFFF) * H + h]);
  }
  for (; j < e; ++j) {
    int2 r = rec[j];
    a0 += __int_as_float(r.y) * bf2f(feat[(size_t)(r.x & 0xFFFF) * H + h]);
  }
  return ((a0 + a1) + (a2 + a3)) + ((a4 + a5) + (a6 + a7));
}

// ---------------------------------------------------------------------------
// Fused gather-aggregate + combine (bf16 feat):
//   out[n] = s[n]*aggA + (1-s[n])*aggK + GAMMA*Dk[n]*feat[n]
// ---------------------------------------------------------------------------
template <int H, bool OUTF32>
__global__ __launch_bounds__(256) void agg_combine(
    const int* __restrict__ rpA, const int2* __restrict__ recA,
    const int* __restrict__ rpK, const int2* __restrict__ recK,
    const unsigned short* __restrict__ feat, const float* __restrict__ s,
    const float* __restrict__ Dk, void* __restrict__ outp, int N) {
  int tid = blockIdx.x * 256 + threadIdx.x;
  int n = tid / H;
  int h = tid % H;
  if (n >= N) return;

  float aA = gather_sum<H>(rpA, recA, feat, n, h);
  float aK = gather_sum<H>(rpK, recK, feat, n, h);

  float sv = s[n];
  float self = bf2f(feat[(size_t)n * H + h]);
  float res = sv * aA + (1.f - sv) * aK + GAMMA * Dk[n] * self;
  if (OUTF32) ((float*)outp)[(size_t)n * H + h] = res;
  else ((unsigned short*)outp)[(size_t)n * H + h] = f2bf(res);
}

// ---------------------------------------------------------------------------
extern "C" void kernel_launch(void* const* d_in, const int* in_sizes, int n_in,
                              void* d_out, int out_size, void* d_ws, size_t ws_size,
                              hipStream_t stream) {
  const float* x = (const float*)d_in[0];
  const int* edge_index = (const int*)d_in[1];
  const float* edge_weight = (const float*)d_in[2];
  const int* knn_edge_index = (const int*)d_in[3];
  const float* knn_edge_weight = (const float*)d_in[4];
  const float* W0 = (const float*)d_in[5];
  const float* W1 = (const float*)d_in[6];
  const float* score0 = (const float*)d_in[7];
  const float* sbias0 = (const float*)d_in[8];
  const float* score1 = (const float*)d_in[9];
  const float* sbias1 = (const float*)d_in[10];
  const float* Dk0 = (const float*)d_in[11];
  const float* Dbias0 = (const float*)d_in[12];
  const float* Dk1 = (const float*)d_in[13];
  const float* Dbias1 = (const float*)d_in[14];

  const int F = in_sizes[7];          // 500
  const int N = in_sizes[0] / F;      // 50000 (< 65536: src packed in 16 bits)
  const int E = in_sizes[2];          // 1.6M
  const int Ek = in_sizes[4];         // 1.0M
  (void)n_in; (void)ws_size; (void)out_size;

  const int nb = (N + 127) / 128;     // 391 dst tiles (<= 512)

  // ---- workspace bump allocator (256B-aligned slices) ----
  char* cur = (char*)d_ws;
  auto alloc = [&](size_t bytes) {
    char* p = cur;
    cur += (bytes + 255) & ~(size_t)255;
    return (void*)p;
  };
  float* sbuf = (float*)alloc((size_t)N * 4);
  float* dkbuf = (float*)alloc((size_t)N * 4);
  int* bcnt2 = (int*)alloc((size_t)2 * nb * 4);   // ONE slice: memset covers both
  int* bcntA = bcnt2;
  int* bcntK = bcnt2 + nb;
  int* boffA = (int*)alloc((size_t)(nb + 1) * 4);
  int* boffK = (int*)alloc((size_t)(nb + 1) * 4);
  int* gcurA = (int*)alloc((size_t)nb * 4);
  int* gcurK = (int*)alloc((size_t)nb * 4);
  int* rpA = (int*)alloc((size_t)(N + 1) * 4);
  int* rpK = (int*)alloc((size_t)(N + 1) * 4);
  int2* recA = (int2*)alloc((size_t)E * 8);       // sorted (exact CSR)
  int2* recK = (int2*)alloc((size_t)Ek * 8);
  unsigned short* Bt0 = (unsigned short*)alloc((size_t)80 * 512 * 2);
  unsigned short* Bt1 = (unsigned short*)alloc((size_t)32 * 64 * 2);
  // UNION region: recRaw (dead after tile_sort) overlaps xW buffers
  // (written only after tile_sort completes; same stream => safe).
  char* uni = (char*)alloc((size_t)(E + Ek) * 8);
  int2* recRawA = (int2*)uni;
  int2* recRawK = recRawA + E;
  unsigned short* xWb = (unsigned short*)uni;                    // N*64
  unsigned short* x1b = xWb + (size_t)N * 64;                    // N*64
  unsigned short* xW1b = x1b + (size_t)N * 64;                   // N*16

  // ---- B transposes (tiny) ----
  build_bt<<<(80 * 512 + 255) / 256, 256, 0, stream>>>(W0, score0, Dk0, Bt0,
                                                       64, F, 512, 80);
  build_bt<<<(32 * 64 + 255) / 256, 256, 0, stream>>>(W1, score1, Dk1, Bt1,
                                                      16, 64, 64, 32);

  // ---- tile binning + exact CSR (reused by both layers) ----
  hipMemsetAsync(bcnt2, 0, (size_t)2 * nb * sizeof(int), stream);
  const int nchA = (E + BIN_CHUNK - 1) / BIN_CHUNK;
  const int nchK = (Ek + BIN_CHUNK - 1) / BIN_CHUNK;
  bucket_count<<<nchA, 256, 0, stream>>>(edge_index, E, bcntA);
  bucket_count<<<nchK, 256, 0, stream>>>(knn_edge_index, Ek, bcntK);
  bucket_scan<<<1, 512, 0, stream>>>(bcntA, nb, boffA, gcurA);
  bucket_scan<<<1, 512, 0, stream>>>(bcntK, nb, boffK, gcurK);
  bin_fill<<<nchA, 256, 0, stream>>>(edge_index, edge_weight, E, gcurA,
                                     recRawA);
  bin_fill<<<nchK, 256, 0, stream>>>(knn_edge_index, knn_edge_weight, Ek,
                                     gcurK, recRawK);
  tile_sort<<<nb, 256, 0, stream>>>(recRawA, boffA, recA, rpA, N, nb);
  tile_sort<<<nb, 256, 0, stream>>>(recRawK, boffK, recK, rpK, N, nb);

  const int gemmBlocks = (N + 63) / 64;

  // ---- Layer 0: F=500 -> H=64 (+gate+Dk) ----
  mfma_linear<512, 5, 4, false><<<gemmBlocks, 256, 0, stream>>>(
      x, Bt0, sbias0, Dbias0, xWb, sbuf, dkbuf, N, F);
  agg_combine<64, false><<<(int)(((size_t)N * 64 + 255) / 256), 256, 0, stream>>>(
      rpA, recA, rpK, recK, xWb, sbuf, dkbuf, x1b, N);

  // ---- Layer 1: H=64 -> O=16 (+gate+Dk) ----
  mfma_linear<64, 2, 1, true><<<gemmBlocks, 256, 0, stream>>>(
      x1b, Bt1, sbias1, Dbias1, xW1b, sbuf, dkbuf, N, 64);
  agg_combine<16, true><<<(int)(((size_t)N * 16 + 255) / 256), 256, 0, stream>>>(
      rpA, recA, rpK, recK, xW1b, sbuf, dkbuf, d_out, N);
}